// Round 1
// baseline (41.506 us; speedup 1.0000x reference)
//
#include <hip/hip_runtime.h>

// Problem constants (from reference): x[64][32768][15] f32, hidden sizes 4/4/4.
#define SEQ   64
#define BATCH 32768
#define FEAT  15
#define SLAB  (BATCH * FEAT)   // dwords per timestep slab of x

__device__ __forceinline__ float fast_rcp(float x) { return __builtin_amdgcn_rcpf(x); }

__device__ __forceinline__ float fast_sigmoid(float x) {
    // 1 / (1 + e^-x); stable at both extremes (rcp(inf)=0).
    return fast_rcp(1.0f + __expf(-x));
}
__device__ __forceinline__ float fast_tanh(float x) {
    // 1 - 2/(1 + e^{2x}); stable at both extremes.
    return 1.0f - 2.0f * fast_rcp(1.0f + __expf(2.0f * x));
}

// Quad (4-lane) DPP move: CTRL = j*0x55 broadcasts lane j of each quad.
template <int CTRL>
__device__ __forceinline__ float qmov(float v) {
    return __int_as_float(
        __builtin_amdgcn_mov_dpp(__float_as_int(v), CTRL, 0xf, 0xf, false));
}

__global__ __launch_bounds__(256) void lstm_fused(
    const float* __restrict__ x,
    const float* __restrict__ w1,  const float* __restrict__ b1,
    const float* __restrict__ w2,  const float* __restrict__ b2,
    const float* __restrict__ wih, const float* __restrict__ whh,
    const float* __restrict__ bih, const float* __restrict__ bhh,
    const float* __restrict__ w3,  const float* __restrict__ b3,
    float* __restrict__ out)
{
    // 4 waves/block; each wave owns 16 batch elements; 4 lanes per element.
    __shared__ float4 lds4[4][2][60];   // [wave][buf][60 float4] = 960 B per buf

    const int tid = threadIdx.x;
    const int w   = tid >> 6;          // wave in block
    const int l   = tid & 63;          // lane
    const int u   = l & 3;             // hidden-unit index this lane owns
    const int e   = l >> 2;            // element within the wave's 16
    const int ewave = blockIdx.x * 64 + w * 16;  // global element base for wave

    // ---- per-lane weights (lane handles hidden unit u of every layer) ----
    float W1[FEAT], W2[4], WI[16], WH[16], BI[4];
#pragma unroll
    for (int f = 0; f < FEAT; ++f) W1[f] = w1[u * FEAT + f];
    const float B1v = b1[u];
#pragma unroll
    for (int j = 0; j < 4; ++j) W2[j] = w2[u * 4 + j];
    const float B2v = b2[u];
#pragma unroll
    for (int g = 0; g < 4; ++g) {
#pragma unroll
        for (int j = 0; j < 4; ++j) {
            WI[g * 4 + j] = wih[(g * 4 + u) * 4 + j];   // torch gate order i,f,g,o
            WH[g * 4 + j] = whh[(g * 4 + u) * 4 + j];
        }
        BI[g] = bih[g * 4 + u] + bhh[g * 4 + u];
    }
    const float W3v = w3[u];
    const float B3v = b3[0];

    float* L0 = (float*)&lds4[w][0][0];
    float* L1 = (float*)&lds4[w][1][0];
    const bool ld = (l < 60);          // 60 lanes * 16 B = 16 elems * 60 B exactly

    // ---- prologue: load slabs 0 and 1, stage slab 0 ----
    float4 rA, rB;
    {
        const float4* g0 = (const float4*)(x + 0 * (size_t)SLAB + (size_t)ewave * FEAT);
        const float4* g1 = (const float4*)(x + 1 * (size_t)SLAB + (size_t)ewave * FEAT);
        if (ld) rA = g0[l];
        if (ld) rB = g1[l];
        if (ld) ((float4*)L0)[l] = rA;
    }

    float h = 0.0f, c = 0.0f;

    auto compute = [&](const float* L) {
        float xv[FEAT];
#pragma unroll
        for (int f = 0; f < FEAT; ++f) xv[f] = L[e * FEAT + f];
        // fc1 (unit u) + relu
        float a1 = B1v;
#pragma unroll
        for (int f = 0; f < FEAT; ++f) a1 = fmaf(W1[f], xv[f], a1);
        const float h1 = fmaxf(a1, 0.0f);
        // fc2 (needs all 4 h1) + sigmoid
        float q0 = qmov<0x00>(h1), q1 = qmov<0x55>(h1), q2 = qmov<0xAA>(h1), q3 = qmov<0xFF>(h1);
        const float a2 = B2v + W2[0] * q0 + W2[1] * q1 + W2[2] * q2 + W2[3] * q3;
        const float h2 = fast_sigmoid(a2);
        // input-to-gate projection (needs all 4 h2)
        q0 = qmov<0x00>(h2); q1 = qmov<0x55>(h2); q2 = qmov<0xAA>(h2); q3 = qmov<0xFF>(h2);
        float gi = BI[0] + WI[0]  * q0 + WI[1]  * q1 + WI[2]  * q2 + WI[3]  * q3;
        float gf = BI[1] + WI[4]  * q0 + WI[5]  * q1 + WI[6]  * q2 + WI[7]  * q3;
        float gg = BI[2] + WI[8]  * q0 + WI[9]  * q1 + WI[10] * q2 + WI[11] * q3;
        float go = BI[3] + WI[12] * q0 + WI[13] * q1 + WI[14] * q2 + WI[15] * q3;
        // recurrent projection (needs all 4 h_prev)
        q0 = qmov<0x00>(h); q1 = qmov<0x55>(h); q2 = qmov<0xAA>(h); q3 = qmov<0xFF>(h);
        gi += WH[0]  * q0 + WH[1]  * q1 + WH[2]  * q2 + WH[3]  * q3;
        gf += WH[4]  * q0 + WH[5]  * q1 + WH[6]  * q2 + WH[7]  * q3;
        gg += WH[8]  * q0 + WH[9]  * q1 + WH[10] * q2 + WH[11] * q3;
        go += WH[12] * q0 + WH[13] * q1 + WH[14] * q2 + WH[15] * q3;
        const float ig = fast_sigmoid(gi);
        const float fg = fast_sigmoid(gf);
        const float gt = fast_tanh(gg);
        const float og = fast_sigmoid(go);
        c = fmaf(fg, c, ig * gt);
        h = og * fast_tanh(c);
    };

    // ---- main loop: 31 iterations x 2 steps, depth-2 prefetch pipeline ----
#pragma unroll 1
    for (int su = 0; su < 31; ++su) {
        const int s = 2 * su;
        const float4* gA = (const float4*)(x + (size_t)(s + 2) * SLAB + (size_t)ewave * FEAT);
        const float4* gB = (const float4*)(x + (size_t)(s + 3) * SLAB + (size_t)ewave * FEAT);
        if (ld) rA = gA[l];            // prefetch step s+2
        compute(L0);                   // step s
        if (ld) ((float4*)L1)[l] = rB; // stage step s+1 (vmcnt wait was covered by compute)
        if (ld) rB = gB[l];            // prefetch step s+3
        compute(L1);                   // step s+1
        if (ld) ((float4*)L0)[l] = rA; // stage step s+2
    }
    // tail: steps 62, 63
    compute(L0);
    if (ld) ((float4*)L1)[l] = rB;
    compute(L1);

    // ---- head: out[e] = sigmoid(sum_u w3[u]*h_u + b3), quad reduction ----
    float p = W3v * h;
    p += qmov<0xB1>(p);   // quad_perm [1,0,3,2]
    p += qmov<0x4E>(p);   // quad_perm [2,3,0,1]
    if (u == 0) out[ewave + e] = fast_sigmoid(p + B3v);
}

extern "C" void kernel_launch(void* const* d_in, const int* in_sizes, int n_in,
                              void* d_out, int out_size, void* d_ws, size_t ws_size,
                              hipStream_t stream) {
    (void)in_sizes; (void)n_in; (void)d_ws; (void)ws_size; (void)out_size;
    const float* x   = (const float*)d_in[0];
    const float* w1  = (const float*)d_in[1];
    const float* b1  = (const float*)d_in[2];
    const float* w2  = (const float*)d_in[3];
    const float* b2  = (const float*)d_in[4];
    const float* wih = (const float*)d_in[5];
    const float* whh = (const float*)d_in[6];
    const float* bih = (const float*)d_in[7];
    const float* bhh = (const float*)d_in[8];
    const float* w3  = (const float*)d_in[9];
    const float* b3  = (const float*)d_in[10];
    float* out = (float*)d_out;

    // 512 blocks x 256 threads = 2048 waves; 4 lanes per batch element.
    lstm_fused<<<dim3(512), dim3(256), 0, stream>>>(
        x, w1, b1, w2, b2, wih, whh, bih, bhh, w3, b3, out);
}